// Round 5
// baseline (58.600 us; speedup 1.0000x reference)
//
#include <hip/hip_runtime.h>
#include <hip/hip_bf16.h>

// KoLeo loss, B=8192, D=256, TOPK=1.
// loss = mean_i( -log( ||x_i - x_{nn(i)}|| + 2*EPS ) ),  x = row-normalize(input)
// nn(i) = argmax_{j!=i} dot(x_i, x_j)  via bf16 MFMA Gram scan (selection only);
// the selected distance is recomputed exactly in fp32.
//
// argmax kernel: swapped-operand 32x32x16 MFMA. Each wave holds 64 OWNED
// columns as TWO B-operand register sets (128 regs, live in AGPRs); streamed
// rows staged through double-buffered XOR-swizzled LDS (zero bank conflicts,
// verified r4). Argmax state is ONE packed float per col-set: low 9 mantissa
// bits of the fp32 dot are replaced by the 9-bit local row id, so a plain
// fmaxf chain tracks (value,index) together -> no vcc chains, no index regs,
// ~200 unified regs total -> 2 waves/SIMD, 2 blocks/CU (the r4 version was
// 272 regs -> 1 wave/SIMD -> full serialization; that was the 42us).

#define NB 8192
#define ND 256
#define ROWB 512          // bytes per row of bf16 x
#define EPSF 1e-8f
#define OWN 256           // owned cols per block (64 per wave)
#define CSL 512           // streamed rows per block slice
#define TROWS 64          // streamed rows per LDS tile (32 KB)
#define NT (CSL / TROWS)  // 8 tiles

typedef __attribute__((ext_vector_type(8))) short short8;
typedef __attribute__((ext_vector_type(16))) float f32x16;
typedef unsigned long long ull;

__device__ __forceinline__ unsigned short f2bf(float f) {
    unsigned int u = __float_as_uint(f);
    unsigned int r = (u + 0x7FFFu + ((u >> 16) & 1u)) >> 16;   // RNE
    return (unsigned short)r;
}

__device__ __forceinline__ unsigned int fkey(float f) {
    unsigned int u = __float_as_uint(f);
    return (u & 0x80000000u) ? ~u : (u | 0x80000000u);
}

__device__ __forceinline__ float packidx(float v, int lr) {
    return __uint_as_float((__float_as_uint(v) & 0xFFFFFE00u) | (unsigned int)lr);
}

__device__ __forceinline__ void gload16(const void* g, void* l) {
    __builtin_amdgcn_global_load_lds(
        (const __attribute__((address_space(1))) unsigned int*)g,
        (__attribute__((address_space(3))) unsigned int*)l,
        16, 0, 0);
}

// ---------------- Phase A: row L2-normalize -> bf16 x, norms; zero `best` ----
__global__ __launch_bounds__(256) void koleo_normalize(const float* __restrict__ s,
                                                       unsigned int* __restrict__ xb_u32,
                                                       float* __restrict__ norms,
                                                       ull* __restrict__ best) {
    const int w = threadIdx.x >> 6, lane = threadIdx.x & 63;
    const int row = blockIdx.x * 4 + w;
    const float4 v = *(const float4*)(s + row * ND + lane * 4);
    float ss = v.x * v.x + v.y * v.y + v.z * v.z + v.w * v.w;
    #pragma unroll
    for (int m = 32; m; m >>= 1) ss += __shfl_xor(ss, m);
    const float nrm = sqrtf(ss);
    const float sc = 1.0f / (nrm + EPSF);
    uint2 pk;
    pk.x = (unsigned int)f2bf(v.x * sc) | ((unsigned int)f2bf(v.y * sc) << 16);
    pk.y = (unsigned int)f2bf(v.z * sc) | ((unsigned int)f2bf(v.w * sc) << 16);
    *(uint2*)(xb_u32 + (row * ND + lane * 4) / 2) = pk;
    if (lane == 0) { norms[row] = nrm; best[row] = 0ull; }
}

// ---------------- Phase B: swapped-operand MFMA argmax ------------------------
// grid (NB/OWN, NB/CSL) = (32, 16); block 256 = 4 waves; 2 blocks/CU.
__global__ __launch_bounds__(256, 2) void koleo_argmax(const short* __restrict__ x,
                                                       ull* __restrict__ best) {
    __shared__ short lds[2][TROWS * ND];   // 2 x 32 KB double buffer
    const int tid = threadIdx.x;
    const int lane = tid & 63;
    const int col = lane & 31;             // A row (streamed) / D col (owned)
    const int h = lane >> 5;               // k-half selector
    const int i0 = blockIdx.x * OWN + (tid >> 6) * 64 + col;  // owned col, set 0
    const int i1 = i0 + 32;                                   // owned col, set 1
    const int sbase = blockIdx.y * CSL;
    const bool hasdiag = ((int)blockIdx.y == ((int)blockIdx.x >> 1));
    const int iloc0 = i0 - sbase, iloc1 = i1 - sbase;
    const char* xc = (const char*)x;

    // owned-col B fragments: 2 sets x 16 k-steps x 8 bf16 (128 regs -> AGPR)
    short8 bfrag[2][16];
    #pragma unroll
    for (int q = 0; q < 2; ++q) {
        const short* bp = x + (size_t)(i0 + 32 * q) * ND + h * 8;
        #pragma unroll
        for (int ks = 0; ks < 16; ++ks) bfrag[q][ks] = *(const short8*)(bp + ks * 16);
    }

    // staging: thread stages 8 x 16B chunks/tile; LDS dest linear,
    // global source pre-swizzled with slot ^= row&31 (involution)
    int soff[8];
    #pragma unroll
    for (int ph = 0; ph < 8; ++ph) {
        const int idx = ph * 256 + tid;
        const int row = idx >> 5, c16 = idx & 31;
        soff[ph] = row * ROWB + ((c16 ^ (row & 31)) << 4);
    }
    const int ldsoff = tid << 4;

    // A ds_read: row (s*32+col), slot (2ks+h) ^ col  (same involution)
    const int colx = col << 4;

    float bd0 = -4.0f, bd1 = -4.0f;
    char* l0 = (char*)&lds[0][0];

    // prologue: stage tile 0
    {
        const char* gt = xc + (size_t)sbase * ROWB;
        #pragma unroll
        for (int ph = 0; ph < 8; ++ph)
            gload16(gt + soff[ph], l0 + ph * 4096 + ldsoff);
    }
    __syncthreads();

    for (int t = 0; t < NT; ++t) {
        const int cur = t & 1;
        // issue next-tile staging BEFORE compute (drained at the barrier)
        if (t + 1 < NT) {
            const char* gt = xc + (size_t)(sbase + (t + 1) * TROWS) * ROWB;
            char* lb = l0 + (cur ^ 1) * (TROWS * ROWB);
            #pragma unroll
            for (int ph = 0; ph < 8; ++ph)
                gload16(gt + soff[ph], lb + ph * 4096 + ldsoff);
        }
        const char* lt = l0 + cur * (TROWS * ROWB);
        #pragma unroll
        for (int s = 0; s < 2; ++s) {
            const char* la = lt + (s * 32 + col) * ROWB;
            f32x16 acc0, acc1;
            #pragma unroll
            for (int z = 0; z < 16; ++z) { acc0[z] = 0.f; acc1[z] = 0.f; }
            #pragma unroll
            for (int ks = 0; ks < 16; ++ks) {
                const short8 a = *(const short8*)(la + (((ks << 5) | (h << 4)) ^ colx));
                acc0 = __builtin_amdgcn_mfma_f32_32x32x16_bf16(a, bfrag[0][ks], acc0, 0, 0, 0);
                acc1 = __builtin_amdgcn_mfma_f32_32x32x16_bf16(a, bfrag[1][ks], acc1, 0, 0, 0);
            }
            // packed-index argmax epilogue: D row = 4h + (r&3) + 8*(r>>2)
            const int lb_ = t * TROWS + s * 32 + (h << 2);
            if (hasdiag) {
                #pragma unroll
                for (int r = 0; r < 16; ++r) {
                    const int lr = lb_ + (r & 3) + 8 * (r >> 2);
                    const float v0 = (lr == iloc0) ? -4.0f : acc0[r];
                    const float v1 = (lr == iloc1) ? -4.0f : acc1[r];
                    bd0 = fmaxf(bd0, packidx(v0, lr));
                    bd1 = fmaxf(bd1, packidx(v1, lr));
                }
            } else {
                #pragma unroll
                for (int r = 0; r < 16; ++r) {
                    const int lr = lb_ + (r & 3) + 8 * (r >> 2);
                    bd0 = fmaxf(bd0, packidx(acc0[r], lr));
                    bd1 = fmaxf(bd1, packidx(acc1[r], lr));
                }
            }
        }
        __syncthreads();
    }

    // merge the two k-halves (disjoint row sets), then global merge
    {
        float o = __shfl_xor(bd0, 32); bd0 = fmaxf(bd0, o);
        o = __shfl_xor(bd1, 32); bd1 = fmaxf(bd1, o);
        if (lane < 32) {
            const int j0 = sbase + (int)(__float_as_uint(bd0) & 511u);
            const int j1 = sbase + (int)(__float_as_uint(bd1) & 511u);
            atomicMax(&best[i0], ((ull)fkey(bd0) << 32) | (unsigned int)j0);
            atomicMax(&best[i1], ((ull)fkey(bd1) << 32) | (unsigned int)j1);
        }
    }
}

// ---------------- Phase C: exact fp32 distances + partial loss sums -----------
// grid NB/16 = 512 blocks; 4 waves/block; each wave handles 4 rows.
__global__ __launch_bounds__(256) void koleo_dist(const float* __restrict__ s,
                                                  const float* __restrict__ norms,
                                                  const ull* __restrict__ best,
                                                  float* __restrict__ partial) {
    __shared__ float wsums[4];
    const int w = threadIdx.x >> 6, lane = threadIdx.x & 63;
    float acc = 0.f;
    #pragma unroll
    for (int t = 0; t < 4; ++t) {
        const int i = blockIdx.x * 16 + w * 4 + t;
        const int j = (int)(best[i] & 0xFFFFFFFFull);
        const float sci = 1.0f / (norms[i] + EPSF);
        const float scj = 1.0f / (norms[j] + EPSF);
        const float4 vi = *(const float4*)(s + i * ND + lane * 4);
        const float4 vj = *(const float4*)(s + j * ND + lane * 4);
        const float dx = vi.x * sci - vj.x * scj;
        const float dy = vi.y * sci - vj.y * scj;
        const float dz = vi.z * sci - vj.z * scj;
        const float dw = vi.w * sci - vj.w * scj;
        float d2 = dx * dx + dy * dy + dz * dz + dw * dw;
        #pragma unroll
        for (int mask = 32; mask; mask >>= 1) d2 += __shfl_xor(d2, mask);
        acc += -logf(sqrtf(d2) + EPSF + EPSF);
    }
    if (lane == 0) wsums[w] = acc;
    __syncthreads();
    if (threadIdx.x == 0) partial[blockIdx.x] = wsums[0] + wsums[1] + wsums[2] + wsums[3];
}

// ---------------- Phase D: final reduce (512 partials) ------------------------
__global__ __launch_bounds__(512) void koleo_final(const float* __restrict__ partial,
                                                   float* __restrict__ out) {
    __shared__ float w8[8];
    float v = partial[threadIdx.x];
    #pragma unroll
    for (int mask = 32; mask; mask >>= 1) v += __shfl_xor(v, mask);
    if ((threadIdx.x & 63) == 0) w8[threadIdx.x >> 6] = v;
    __syncthreads();
    if (threadIdx.x == 0) {
        float t = 0.f;
        #pragma unroll
        for (int k = 0; k < 8; ++k) t += w8[k];
        out[0] = t / (float)NB;
    }
}

extern "C" void kernel_launch(void* const* d_in, const int* in_sizes, int n_in,
                              void* d_out, int out_size, void* d_ws, size_t ws_size,
                              hipStream_t stream) {
    const float* s = (const float*)d_in[0];
    float* out = (float*)d_out;
    char* ws = (char*)d_ws;

    // ws layout
    unsigned int* xb = (unsigned int*)ws;                                   // 4 MiB bf16 x
    float* norms = (float*)(ws + 4 * 1024 * 1024);                          // 32 KiB
    ull* best = (ull*)(ws + 4 * 1024 * 1024 + 32 * 1024);                   // 64 KiB
    float* partial = (float*)(ws + 4 * 1024 * 1024 + 96 * 1024);            // 2 KiB

    koleo_normalize<<<NB / 4, 256, 0, stream>>>(s, xb, norms, best);
    koleo_argmax<<<dim3(NB / OWN, NB / CSL), 256, 0, stream>>>((const short*)xb, best);
    koleo_dist<<<NB / 16, 256, 0, stream>>>(s, norms, best, partial);
    koleo_final<<<1, 512, 0, stream>>>(partial, out);
}

// Round 7
// 48.656 us; speedup vs baseline: 1.2044x; 1.2044x over previous
//
#include <hip/hip_runtime.h>
#include <hip/hip_bf16.h>

// KoLeo loss, B=8192, D=256, TOPK=1.
// loss = mean_i( -log( ||x_i - x_{nn(i)}|| + 2*EPS ) ),  x = row-normalize(input)
// nn(i) = argmax_{j!=i} dot(x_i, x_j)  via bf16 MFMA Gram scan (selection only);
// the selected distance is recomputed exactly in fp32.
//
// argmax kernel: swapped-operand 32x32x16 MFMA, 64 owned cols/wave (2 B-sets,
// 128 regs), streamed rows via double-buffered XOR-swizzled LDS (0 conflicts,
// verified r4/r5). r5 lesson: ~260 unified regs -> 1 wave/SIMD -> full
// serialization. This version diets to ~215 unified regs (2 waves/SIMD):
//   - 16 persistent ds_read vaddr regs; all tile/s/buffer selection goes into
//     the 16-bit offset immediate (max 49152+16383 = 65535, fits exactly).
//   - epilogue packs the 9-bit local row id into the low mantissa bits:
//     and_or + max = ~3 VALU/elem, 1 temp, no vcc chains, no index regs.

#define NB 8192
#define ND 256
#define ROWB 512          // bytes per row of bf16 x
#define EPSF 1e-8f
#define OWN 256           // owned cols per block (64 per wave)
#define CSL 512           // streamed rows per block slice
#define TROWS 64          // streamed rows per LDS tile (32 KB)
#define NT (CSL / TROWS)  // 8 tiles
#define TBYTES (TROWS * ROWB)

typedef __attribute__((ext_vector_type(8))) short short8;
typedef __attribute__((ext_vector_type(16))) float f32x16;
typedef unsigned long long ull;

__device__ __forceinline__ unsigned short f2bf(float f) {
    unsigned int u = __float_as_uint(f);
    unsigned int r = (u + 0x7FFFu + ((u >> 16) & 1u)) >> 16;   // RNE
    return (unsigned short)r;
}

__device__ __forceinline__ unsigned int fkey(float f) {
    unsigned int u = __float_as_uint(f);
    return (u & 0x80000000u) ? ~u : (u | 0x80000000u);
}

__device__ __forceinline__ void gload16(const void* g, void* l) {
    __builtin_amdgcn_global_load_lds(
        (const __attribute__((address_space(1))) unsigned int*)g,
        (__attribute__((address_space(3))) unsigned int*)l,
        16, 0, 0);
}

// ---------------- Phase A: row L2-normalize -> bf16 x, norms; zero `best` ----
__global__ __launch_bounds__(256) void koleo_normalize(const float* __restrict__ s,
                                                       unsigned int* __restrict__ xb_u32,
                                                       float* __restrict__ norms,
                                                       ull* __restrict__ best) {
    const int w = threadIdx.x >> 6, lane = threadIdx.x & 63;
    const int row = blockIdx.x * 4 + w;
    const float4 v = *(const float4*)(s + row * ND + lane * 4);
    float ss = v.x * v.x + v.y * v.y + v.z * v.z + v.w * v.w;
    #pragma unroll
    for (int m = 32; m; m >>= 1) ss += __shfl_xor(ss, m);
    const float nrm = sqrtf(ss);
    const float sc = 1.0f / (nrm + EPSF);
    uint2 pk;
    pk.x = (unsigned int)f2bf(v.x * sc) | ((unsigned int)f2bf(v.y * sc) << 16);
    pk.y = (unsigned int)f2bf(v.z * sc) | ((unsigned int)f2bf(v.w * sc) << 16);
    *(uint2*)(xb_u32 + (row * ND + lane * 4) / 2) = pk;
    if (lane == 0) { norms[row] = nrm; best[row] = 0ull; }
}

// ---------------- Phase B: swapped-operand MFMA argmax ------------------------
// grid (NB/OWN, NB/CSL) = (32, 16); block 256 = 4 waves; 2 blocks/CU.
__global__ __launch_bounds__(256, 2) void koleo_argmax(const short* __restrict__ x,
                                                       ull* __restrict__ best) {
    __shared__ short lds[2][TROWS * ND];   // 2 x 32 KB double buffer
    const int tid = threadIdx.x;
    const int lane = tid & 63;
    const int col = lane & 31;             // A row (streamed) / D col (owned)
    const int h = lane >> 5;               // k-half selector
    const int hq = h << 2;                 // D-row base within 8-group
    const int i0 = blockIdx.x * OWN + (tid >> 6) * 64 + col;  // owned col, set 0
    const int i1 = i0 + 32;                                   // owned col, set 1
    const int sbase = blockIdx.y * CSL;
    const bool hasdiag = ((int)blockIdx.y == ((int)blockIdx.x >> 1));
    const int iloc0 = i0 - sbase, iloc1 = i1 - sbase;
    const char* xc = (const char*)x;
    char* ldsc = (char*)&lds[0][0];

    // owned-col B fragments: 2 sets x 16 k-steps x 8 bf16 (128 regs)
    short8 bfrag[2][16];
    #pragma unroll
    for (int q = 0; q < 2; ++q) {
        const short* bp = x + (size_t)(i0 + 32 * q) * ND + h * 8;
        #pragma unroll
        for (int ks = 0; ks < 16; ++ks) bfrag[q][ks] = *(const short8*)(bp + ks * 16);
    }

    // staging: thread stages 8 x 16B chunks/tile; LDS dest linear,
    // global source pre-swizzled with slot ^= row&31 (involution)
    int soff[8];
    #pragma unroll
    for (int ph = 0; ph < 8; ++ph) {
        const int idx = ph * 256 + tid;
        const int row = idx >> 5, c16 = idx & 31;
        soff[ph] = row * ROWB + ((c16 ^ (row & 31)) << 4);
    }
    const int ldsoff = tid << 4;

    // persistent ds_read vaddrs: aoff[ks] = col*512 + ((ks<<5 | h<<4) ^ col<<4)
    // all (buffer, s) selection goes into the offset immediate (<= 65535).
    const int colx = col << 4;
    int aoff[16];
    #pragma unroll
    for (int ks = 0; ks < 16; ++ks)
        aoff[ks] = col * ROWB + (((ks << 5) | (h << 4)) ^ colx);

    float bd0 = -4.0f, bd1 = -4.0f;

    // prologue: stage tile 0 into buffer 0
    {
        const char* gt = xc + (size_t)sbase * ROWB;
        #pragma unroll
        for (int ph = 0; ph < 8; ++ph)
            gload16(gt + soff[ph], ldsc + ph * 4096 + ldsoff);
    }
    __syncthreads();

    #define KL_COMPUTE(BUF, TILE)                                                 \
        {                                                                         \
            _Pragma("unroll")                                                     \
            for (int s = 0; s < 2; ++s) {                                         \
                f32x16 acc0, acc1;                                                \
                _Pragma("unroll")                                                 \
                for (int z = 0; z < 16; ++z) { acc0[z] = 0.f; acc1[z] = 0.f; }    \
                _Pragma("unroll")                                                 \
                for (int ks = 0; ks < 16; ++ks) {                                 \
                    const short8 a = *(const short8*)(ldsc + aoff[ks] +           \
                                       (BUF) * TBYTES + s * (32 * ROWB));         \
                    acc0 = __builtin_amdgcn_mfma_f32_32x32x16_bf16(a, bfrag[0][ks], acc0, 0, 0, 0); \
                    acc1 = __builtin_amdgcn_mfma_f32_32x32x16_bf16(a, bfrag[1][ks], acc1, 0, 0, 0); \
                }                                                                 \
                const int vb = (((TILE) << 6) | (s << 5)) | hq;                   \
                if (hasdiag) {                                                    \
                    _Pragma("unroll")                                             \
                    for (int r = 0; r < 16; ++r) {                                \
                        const int rofs = (r & 3) + 8 * (r >> 2);                  \
                        const int lr = vb | rofs;                                 \
                        const float v0 = (lr == iloc0) ? -4.0f : acc0[r];         \
                        const float v1 = (lr == iloc1) ? -4.0f : acc1[r];         \
                        bd0 = fmaxf(bd0, __uint_as_float((__float_as_uint(v0) & 0xFFFFFE00u) | (unsigned)lr)); \
                        bd1 = fmaxf(bd1, __uint_as_float((__float_as_uint(v1) & 0xFFFFFE00u) | (unsigned)lr)); \
                    }                                                             \
                } else {                                                          \
                    _Pragma("unroll")                                             \
                    for (int r = 0; r < 16; ++r) {                                \
                        const int rofs = (r & 3) + 8 * (r >> 2);                  \
                        const int lr = vb | rofs;                                 \
                        bd0 = fmaxf(bd0, __uint_as_float((__float_as_uint(acc0[r]) & 0xFFFFFE00u) | (unsigned)lr)); \
                        bd1 = fmaxf(bd1, __uint_as_float((__float_as_uint(acc1[r]) & 0xFFFFFE00u) | (unsigned)lr)); \
                    }                                                             \
                }                                                                 \
            }                                                                     \
        }

    // tile loop unrolled x2 so buffer bases are compile-time immediates
    for (int tt = 0; tt < NT / 2; ++tt) {
        const int t0 = 2 * tt, t1 = 2 * tt + 1;
        // phase 0: compute buffer 0 (tile t0), stage tile t1 -> buffer 1
        {
            const char* gt = xc + (size_t)(sbase + t1 * TROWS) * ROWB;
            #pragma unroll
            for (int ph = 0; ph < 8; ++ph)
                gload16(gt + soff[ph], ldsc + TBYTES + ph * 4096 + ldsoff);
        }
        KL_COMPUTE(0, t0)
        __syncthreads();
        // phase 1: compute buffer 1 (tile t1), stage tile t1+1 -> buffer 0
        if (t1 + 1 < NT) {
            const char* gt = xc + (size_t)(sbase + (t1 + 1) * TROWS) * ROWB;
            #pragma unroll
            for (int ph = 0; ph < 8; ++ph)
                gload16(gt + soff[ph], ldsc + ph * 4096 + ldsoff);
        }
        KL_COMPUTE(1, t1)
        __syncthreads();
    }

    // merge the two k-halves (disjoint row sets), then global merge
    {
        float o = __shfl_xor(bd0, 32); bd0 = fmaxf(bd0, o);
        o = __shfl_xor(bd1, 32); bd1 = fmaxf(bd1, o);
        if (lane < 32) {
            const int j0 = sbase + (int)(__float_as_uint(bd0) & 511u);
            const int j1 = sbase + (int)(__float_as_uint(bd1) & 511u);
            atomicMax(&best[i0], ((ull)fkey(bd0) << 32) | (unsigned int)j0);
            atomicMax(&best[i1], ((ull)fkey(bd1) << 32) | (unsigned int)j1);
        }
    }
}

// ---------------- Phase C: exact fp32 distances + partial loss sums -----------
// grid NB/16 = 512 blocks; 4 waves/block; each wave handles 4 rows.
__global__ __launch_bounds__(256) void koleo_dist(const float* __restrict__ s,
                                                  const float* __restrict__ norms,
                                                  const ull* __restrict__ best,
                                                  float* __restrict__ partial) {
    __shared__ float wsums[4];
    const int w = threadIdx.x >> 6, lane = threadIdx.x & 63;
    float acc = 0.f;
    #pragma unroll
    for (int t = 0; t < 4; ++t) {
        const int i = blockIdx.x * 16 + w * 4 + t;
        const int j = (int)(best[i] & 0xFFFFFFFFull);
        const float sci = 1.0f / (norms[i] + EPSF);
        const float scj = 1.0f / (norms[j] + EPSF);
        const float4 vi = *(const float4*)(s + i * ND + lane * 4);
        const float4 vj = *(const float4*)(s + j * ND + lane * 4);
        const float dx = vi.x * sci - vj.x * scj;
        const float dy = vi.y * sci - vj.y * scj;
        const float dz = vi.z * sci - vj.z * scj;
        const float dw = vi.w * sci - vj.w * scj;
        float d2 = dx * dx + dy * dy + dz * dz + dw * dw;
        #pragma unroll
        for (int mask = 32; mask; mask >>= 1) d2 += __shfl_xor(d2, mask);
        acc += -logf(sqrtf(d2) + EPSF + EPSF);
    }
    if (lane == 0) wsums[w] = acc;
    __syncthreads();
    if (threadIdx.x == 0) partial[blockIdx.x] = wsums[0] + wsums[1] + wsums[2] + wsums[3];
}

// ---------------- Phase D: final reduce (512 partials) ------------------------
__global__ __launch_bounds__(512) void koleo_final(const float* __restrict__ partial,
                                                   float* __restrict__ out) {
    __shared__ float w8[8];
    float v = partial[threadIdx.x];
    #pragma unroll
    for (int mask = 32; mask; mask >>= 1) v += __shfl_xor(v, mask);
    if ((threadIdx.x & 63) == 0) w8[threadIdx.x >> 6] = v;
    __syncthreads();
    if (threadIdx.x == 0) {
        float t = 0.f;
        #pragma unroll
        for (int k = 0; k < 8; ++k) t += w8[k];
        out[0] = t / (float)NB;
    }
}

extern "C" void kernel_launch(void* const* d_in, const int* in_sizes, int n_in,
                              void* d_out, int out_size, void* d_ws, size_t ws_size,
                              hipStream_t stream) {
    const float* s = (const float*)d_in[0];
    float* out = (float*)d_out;
    char* ws = (char*)d_ws;

    // ws layout
    unsigned int* xb = (unsigned int*)ws;                                   // 4 MiB bf16 x
    float* norms = (float*)(ws + 4 * 1024 * 1024);                          // 32 KiB
    ull* best = (ull*)(ws + 4 * 1024 * 1024 + 32 * 1024);                   // 64 KiB
    float* partial = (float*)(ws + 4 * 1024 * 1024 + 96 * 1024);            // 2 KiB

    koleo_normalize<<<NB / 4, 256, 0, stream>>>(s, xb, norms, best);
    koleo_argmax<<<dim3(NB / OWN, NB / CSL), 256, 0, stream>>>((const short*)xb, best);
    koleo_dist<<<NB / 16, 256, 0, stream>>>(s, norms, best, partial);
    koleo_final<<<1, 512, 0, stream>>>(partial, out);
}